// Round 1
// baseline (567.896 us; speedup 1.0000x reference)
//
#include <hip/hip_runtime.h>

#define N 256
#define BLK 1024
#define RPT 8   // rows per thread
#define CPT 8   // cols per thread
#define NWAVE 16

__device__ __forceinline__ float wred_max32(float v) {
  v = fmaxf(v, __shfl_xor(v, 16));
  v = fmaxf(v, __shfl_xor(v, 8));
  v = fmaxf(v, __shfl_xor(v, 4));
  v = fmaxf(v, __shfl_xor(v, 2));
  v = fmaxf(v, __shfl_xor(v, 1));
  return v;
}
__device__ __forceinline__ float wred_sum32(float v) {
  v += __shfl_xor(v, 16);
  v += __shfl_xor(v, 8);
  v += __shfl_xor(v, 4);
  v += __shfl_xor(v, 2);
  v += __shfl_xor(v, 1);
  return v;
}

// One block = one 256x256 matrix. Thread (rg,cg) owns an 8x8 subtile:
// rows rg*8..+7, cols cg*8..+7, rg = tid>>5 in [0,32), cg = tid&31.
// Sinkhorn in dual form: la = b - U_i - V_j with b static in registers.
__global__ __launch_bounds__(BLK) void sinkhorn_kernel(
    const float* __restrict__ x, float* __restrict__ out, int n_iters) {
  __shared__ __align__(16) float lds_red[NWAVE * N];  // 16 partials per column
  __shared__ __align__(16) float lds_M[N];
  __shared__ __align__(16) float lds_V[N];

  const int tid = threadIdx.x;
  const int cg = tid & 31;
  const int rg = tid >> 5;
  const int wv = tid >> 6;           // wave index 0..15
  const int r0 = rg * RPT;
  const int c0 = cg * CPT;
  const long mat = blockIdx.x;
  // b = x * log2(e)/T, T = 0.01
  const float SCALE = 144.2695040888963407f;

  float b[RPT][CPT];
  const float4* __restrict__ src =
      reinterpret_cast<const float4*>(x + mat * (long)(N * N));
  #pragma unroll
  for (int r = 0; r < RPT; ++r) {
    int base = ((r0 + r) * N + c0) >> 2;
    float4 v0 = src[base];
    float4 v1 = src[base + 1];
    b[r][0] = v0.x * SCALE; b[r][1] = v0.y * SCALE;
    b[r][2] = v0.z * SCALE; b[r][3] = v0.w * SCALE;
    b[r][4] = v1.x * SCALE; b[r][5] = v1.y * SCALE;
    b[r][6] = v1.z * SCALE; b[r][7] = v1.w * SCALE;
  }

  float U[RPT], V[CPT];
  #pragma unroll
  for (int c = 0; c < CPT; ++c) V[c] = 0.f;

  for (int it = 0; it < n_iters; ++it) {
    // ---------- row step: U_i = lse_j(b_ij - V_j), butterfly over 32 lanes
    #pragma unroll
    for (int r = 0; r < RPT; ++r) {
      float m = -3.0e38f;
      #pragma unroll
      for (int c = 0; c < CPT; ++c) m = fmaxf(m, b[r][c] - V[c]);
      m = wred_max32(m);
      float s = 0.f;
      #pragma unroll
      for (int c = 0; c < CPT; ++c)
        s += __builtin_amdgcn_exp2f(b[r][c] - V[c] - m);
      s = wred_sum32(s);
      U[r] = m + __builtin_amdgcn_logf(s);   // v_log_f32 = log2
    }

    // ---------- col step: V_j = lse_i(b_ij - U_i), cross-wave via LDS
    // pass A: column max
    float pm[CPT];
    #pragma unroll
    for (int c = 0; c < CPT; ++c) pm[c] = -3.0e38f;
    #pragma unroll
    for (int r = 0; r < RPT; ++r) {
      float u = U[r];
      #pragma unroll
      for (int c = 0; c < CPT; ++c) pm[c] = fmaxf(pm[c], b[r][c] - u);
    }
    // combine the two row-groups that share a wave (lane ^ 32, same cols)
    #pragma unroll
    for (int c = 0; c < CPT; ++c) pm[c] = fmaxf(pm[c], __shfl_xor(pm[c], 32));
    if ((tid & 63) < 32) {
      float4* dst = reinterpret_cast<float4*>(&lds_red[wv * N + c0]);
      dst[0] = make_float4(pm[0], pm[1], pm[2], pm[3]);
      dst[1] = make_float4(pm[4], pm[5], pm[6], pm[7]);
    }
    __syncthreads();
    float colM = 0.f;
    if (tid < N) {
      colM = lds_red[tid];
      #pragma unroll
      for (int p = 1; p < NWAVE; ++p) colM = fmaxf(colM, lds_red[p * N + tid]);
      lds_M[tid] = colM;
    }
    __syncthreads();
    float Mo[CPT];
    {
      const float4* mp = reinterpret_cast<const float4*>(&lds_M[c0]);
      float4 m0 = mp[0], m1 = mp[1];
      Mo[0] = m0.x; Mo[1] = m0.y; Mo[2] = m0.z; Mo[3] = m0.w;
      Mo[4] = m1.x; Mo[5] = m1.y; Mo[6] = m1.z; Mo[7] = m1.w;
    }
    // pass B: column sum of 2^(b - U - M)
    float ps[CPT];
    #pragma unroll
    for (int c = 0; c < CPT; ++c) ps[c] = 0.f;
    #pragma unroll
    for (int r = 0; r < RPT; ++r) {
      float u = U[r];
      #pragma unroll
      for (int c = 0; c < CPT; ++c)
        ps[c] += __builtin_amdgcn_exp2f(b[r][c] - u - Mo[c]);
    }
    #pragma unroll
    for (int c = 0; c < CPT; ++c) ps[c] += __shfl_xor(ps[c], 32);
    if ((tid & 63) < 32) {
      float4* dst = reinterpret_cast<float4*>(&lds_red[wv * N + c0]);
      dst[0] = make_float4(ps[0], ps[1], ps[2], ps[3]);
      dst[1] = make_float4(ps[4], ps[5], ps[6], ps[7]);
    }
    __syncthreads();
    if (tid < N) {
      float s = lds_red[tid];
      #pragma unroll
      for (int p = 1; p < NWAVE; ++p) s += lds_red[p * N + tid];
      lds_V[tid] = colM + __builtin_amdgcn_logf(s);
    }
    __syncthreads();
    {
      const float4* vp = reinterpret_cast<const float4*>(&lds_V[c0]);
      float4 v0 = vp[0], v1 = vp[1];
      V[0] = v0.x; V[1] = v0.y; V[2] = v0.z; V[3] = v0.w;
      V[4] = v1.x; V[5] = v1.y; V[6] = v1.z; V[7] = v1.w;
    }
  }

  // ---------- output: P = 2^(b - U_i - V_j)
  float4* __restrict__ dst =
      reinterpret_cast<float4*>(out + mat * (long)(N * N));
  #pragma unroll
  for (int r = 0; r < RPT; ++r) {
    float u = U[r];
    float4 o0, o1;
    o0.x = __builtin_amdgcn_exp2f(b[r][0] - u - V[0]);
    o0.y = __builtin_amdgcn_exp2f(b[r][1] - u - V[1]);
    o0.z = __builtin_amdgcn_exp2f(b[r][2] - u - V[2]);
    o0.w = __builtin_amdgcn_exp2f(b[r][3] - u - V[3]);
    o1.x = __builtin_amdgcn_exp2f(b[r][4] - u - V[4]);
    o1.y = __builtin_amdgcn_exp2f(b[r][5] - u - V[5]);
    o1.z = __builtin_amdgcn_exp2f(b[r][6] - u - V[6]);
    o1.w = __builtin_amdgcn_exp2f(b[r][7] - u - V[7]);
    int base = ((r0 + r) * N + c0) >> 2;
    dst[base] = o0;
    dst[base + 1] = o1;
  }
}

extern "C" void kernel_launch(void* const* d_in, const int* in_sizes, int n_in,
                              void* d_out, int out_size, void* d_ws, size_t ws_size,
                              hipStream_t stream) {
  const float* x = (const float*)d_in[0];
  float* out = (float*)d_out;
  int B = in_sizes[0] / (N * N);
  hipLaunchKernelGGL(sinkhorn_kernel, dim3(B), dim3(BLK), 0, stream, x, out, 21);
}

// Round 2
// 371.463 us; speedup vs baseline: 1.5288x; 1.5288x over previous
//
#include <hip/hip_runtime.h>

#define N 256
#define BLK 1024
#define RPT 8   // rows per thread (contiguous)
#define CPT 8   // cols per thread (stride 32: col = cg + 32k)
#define NWAVE 16

__device__ __forceinline__ float wred_max32(float v) {
  v = fmaxf(v, __shfl_xor(v, 16));
  v = fmaxf(v, __shfl_xor(v, 8));
  v = fmaxf(v, __shfl_xor(v, 4));
  v = fmaxf(v, __shfl_xor(v, 2));
  v = fmaxf(v, __shfl_xor(v, 1));
  return v;
}
__device__ __forceinline__ float wred_sum32(float v) {
  v += __shfl_xor(v, 16);
  v += __shfl_xor(v, 8);
  v += __shfl_xor(v, 4);
  v += __shfl_xor(v, 2);
  v += __shfl_xor(v, 1);
  return v;
}

// One block = one 256x256 matrix, 16 waves.
// Thread (rg = tid>>5, cg = tid&31) owns rows rg*8..+7, cols cg+32k (k=0..7).
// Sinkhorn in dual-potential form: la = b - U_i - V_j, b static in registers.
// All math in log2 domain: b = x * log2(e)/T.
__global__ __launch_bounds__(BLK, 4) void sinkhorn_kernel(
    const float* __restrict__ x, float* __restrict__ out, int n_iters) {
  __shared__ float lds_m[NWAVE * N];  // per-wave partial col max
  __shared__ float lds_s[NWAVE * N];  // per-wave partial col sum
  __shared__ float lds_V[N];

  const int tid = threadIdx.x;
  const int cg = tid & 31;
  const int rg = tid >> 5;
  const int wv = tid >> 6;  // wave index 0..15
  const int r0 = rg * RPT;
  const long mat = blockIdx.x;
  const float SCALE = 144.2695040888963407f;  // log2(e)/0.01

  const float* __restrict__ src = x + mat * (long)(N * N);
  float b[RPT][CPT];
  #pragma unroll
  for (int r = 0; r < RPT; ++r) {
    #pragma unroll
    for (int c = 0; c < CPT; ++c)
      b[r][c] = src[(r0 + r) * N + cg + c * 32] * SCALE;
  }

  float U[RPT], V[CPT];
  #pragma unroll
  for (int c = 0; c < CPT; ++c) V[c] = 0.f;

  for (int it = 0; it < n_iters; ++it) {
    // ---- row step: U_i = lse2_j(b_ij - V_j); butterfly over the 32 lanes
    // of this row group (lanes sharing rg live in one 32-lane half-wave).
    #pragma unroll
    for (int r = 0; r < RPT; ++r) {
      float m = -3.0e38f;
      #pragma unroll
      for (int c = 0; c < CPT; ++c) m = fmaxf(m, b[r][c] - V[c]);
      m = wred_max32(m);
      float s = 0.f;
      #pragma unroll
      for (int c = 0; c < CPT; ++c)
        s += __builtin_amdgcn_exp2f(b[r][c] - V[c] - m);
      s = wred_sum32(s);
      U[r] = m + __builtin_amdgcn_logf(s);  // v_log_f32 = log2
    }

    // ---- col step: V_j = lse2_i(b_ij - U_i), online (max,sum) pairs.
    float lm[CPT], ls[CPT];
    #pragma unroll
    for (int c = 0; c < CPT; ++c) lm[c] = -3.0e38f;
    #pragma unroll
    for (int r = 0; r < RPT; ++r) {
      float u = U[r];
      #pragma unroll
      for (int c = 0; c < CPT; ++c) lm[c] = fmaxf(lm[c], b[r][c] - u);
    }
    #pragma unroll
    for (int c = 0; c < CPT; ++c) {
      float s = 0.f;
      #pragma unroll
      for (int r = 0; r < RPT; ++r)
        s += __builtin_amdgcn_exp2f(b[r][c] - U[r] - lm[c]);
      ls[c] = s;
    }
    // merge the two row-groups sharing this wave (lane ^ 32, same cols)
    #pragma unroll
    for (int c = 0; c < CPT; ++c) {
      float om = __shfl_xor(lm[c], 32);
      float os = __shfl_xor(ls[c], 32);
      float M2 = fmaxf(lm[c], om);
      ls[c] = ls[c] * __builtin_amdgcn_exp2f(lm[c] - M2) +
              os * __builtin_amdgcn_exp2f(om - M2);
      lm[c] = M2;
    }
    if ((tid & 63) < 32) {
      #pragma unroll
      for (int c = 0; c < CPT; ++c) {
        lds_m[wv * N + cg + c * 32] = lm[c];  // lane-distinct banks
        lds_s[wv * N + cg + c * 32] = ls[c];
      }
    }
    __syncthreads();
    if (tid < N) {
      float M = lds_m[tid];
      #pragma unroll
      for (int p = 1; p < NWAVE; ++p) M = fmaxf(M, lds_m[p * N + tid]);
      float S = 0.f;
      #pragma unroll
      for (int p = 0; p < NWAVE; ++p)
        S += lds_s[p * N + tid] *
             __builtin_amdgcn_exp2f(lds_m[p * N + tid] - M);
      lds_V[tid] = M + __builtin_amdgcn_logf(S);
    }
    __syncthreads();
    #pragma unroll
    for (int c = 0; c < CPT; ++c) V[c] = lds_V[cg + c * 32];
  }

  // ---- output: P = 2^(b - U_i - V_j), coalesced scalar stores
  float* __restrict__ dst = out + mat * (long)(N * N);
  #pragma unroll
  for (int r = 0; r < RPT; ++r) {
    float u = U[r];
    #pragma unroll
    for (int c = 0; c < CPT; ++c)
      dst[(r0 + r) * N + cg + c * 32] =
          __builtin_amdgcn_exp2f(b[r][c] - u - V[c]);
  }
}

extern "C" void kernel_launch(void* const* d_in, const int* in_sizes, int n_in,
                              void* d_out, int out_size, void* d_ws, size_t ws_size,
                              hipStream_t stream) {
  const float* x = (const float*)d_in[0];
  float* out = (float*)d_out;
  int B = in_sizes[0] / (N * N);
  hipLaunchKernelGGL(sinkhorn_kernel, dim3(B), dim3(BLK), 0, stream, x, out, 21);
}